// Round 6
// baseline (2676.272 us; speedup 1.0000x reference)
//
#include <hip/hip_runtime.h>

#define N_NODES 100000
#define N_EDGES 1200000
#define DIM 64
#define N_GRAPHS 128
#define N_LAYERS 5

#define NBUCKETS 782          // ceil(100000/128)
#define BCAP 2048             // per-bucket capacity (mean 1534, +13 sigma)
#define CHUNK 8192            // edges per bin block
#define NPARTS 13             // srcPart = src>>13 -> 0..12 (1MB bf16 window each)

#define POOL_CH 196
#define POOL_BLOCKS ((N_NODES + POOL_CH - 1) / POOL_CH)

#define ZSTRIDE 68

typedef unsigned short ushort_t;
typedef unsigned int uint_t;

__device__ __forceinline__ float bf2f(uint_t s) {
  return __uint_as_float(s << 16);
}
__device__ __forceinline__ ushort_t f2bf(float f) {
  uint_t u = __float_as_uint(f);
  uint_t r = u + 0x7fffu + ((u >> 16) & 1u);   // RNE
  return (ushort_t)(r >> 16);
}
__device__ __forceinline__ uint_t pack2(float a, float b) {
  return (uint_t)f2bf(a) | ((uint_t)f2bf(b) << 16);
}

// ---------------- fp32 -> bf16 convert (x only, once) ----------------

__global__ __launch_bounds__(256) void conv_kernel(const float* __restrict__ x,
                                                   ushort_t* __restrict__ xb) {
  int i = blockIdx.x * 256 + threadIdx.x;
  int base = i * 8;
  if (base >= N_NODES * DIM) return;
  float4 a = *(const float4*)(x + base);
  float4 b = *(const float4*)(x + base + 4);
  uint4 o;
  o.x = pack2(a.x, a.y);
  o.y = pack2(a.z, a.w);
  o.z = pack2(b.x, b.y);
  o.w = pack2(b.z, b.w);
  *(uint4*)(xb + base) = o;
}

// ---------------- CSR build stage 1: LDS multisplit into 782 buckets ----------------

__global__ __launch_bounds__(256) void bin_kernel(const int* __restrict__ src,
                                                  const int* __restrict__ dst,
                                                  int* __restrict__ gCursor,
                                                  uint_t* __restrict__ gPairs) {
  __shared__ int hist[NBUCKETS];
  __shared__ int lstart[NBUCKETS];
  __shared__ int lcur[NBUCKETS];
  __shared__ int gbase[NBUCKETS];
  __shared__ uint_t pairbuf[CHUNK];
  __shared__ ushort_t bidbuf[CHUNK];
  __shared__ int wsum[4];

  const int t = threadIdx.x;
  const int e0 = blockIdx.x * CHUNK;
  const int ecnt = min(CHUNK, N_EDGES - e0);

  for (int i = t; i < NBUCKETS; i += 256) hist[i] = 0;
  __syncthreads();

  for (int i = t; i < ecnt; i += 256) {
    int d = dst[e0 + i];
    atomicAdd(&hist[d >> 7], 1);
  }
  __syncthreads();

  const int base4 = t * 4;
  int h0 = 0, h1 = 0, h2 = 0, h3 = 0;
  if (base4 + 0 < NBUCKETS) h0 = hist[base4 + 0];
  if (base4 + 1 < NBUCKETS) h1 = hist[base4 + 1];
  if (base4 + 2 < NBUCKETS) h2 = hist[base4 + 2];
  if (base4 + 3 < NBUCKETS) h3 = hist[base4 + 3];
  int tsum = h0 + h1 + h2 + h3;
  int lane = t & 63, wid = t >> 6;
  int inc = tsum;
  #pragma unroll
  for (int off = 1; off < 64; off <<= 1) {
    int v = __shfl_up(inc, off);
    if (lane >= off) inc += v;
  }
  if (lane == 63) wsum[wid] = inc;
  __syncthreads();
  int wadd = 0;
  for (int w = 0; w < wid; ++w) wadd += wsum[w];
  int ex = wadd + inc - tsum;
  if (base4 + 0 < NBUCKETS) { lstart[base4 + 0] = ex; lcur[base4 + 0] = ex; } ex += h0;
  if (base4 + 1 < NBUCKETS) { lstart[base4 + 1] = ex; lcur[base4 + 1] = ex; } ex += h1;
  if (base4 + 2 < NBUCKETS) { lstart[base4 + 2] = ex; lcur[base4 + 2] = ex; } ex += h2;
  if (base4 + 3 < NBUCKETS) { lstart[base4 + 3] = ex; lcur[base4 + 3] = ex; }
  __syncthreads();

  for (int i = t; i < ecnt; i += 256) {
    int s = src[e0 + i];
    int d = dst[e0 + i];
    int b = d >> 7;
    int p = atomicAdd(&lcur[b], 1);
    pairbuf[p] = (uint_t)s | ((uint_t)(d & 127) << 17);
    bidbuf[p] = (ushort_t)b;
  }
  __syncthreads();

  for (int b = t; b < NBUCKETS; b += 256) {
    int cnt = lcur[b] - lstart[b];
    gbase[b] = cnt ? atomicAdd(&gCursor[b], cnt) : 0;
  }
  __syncthreads();

  for (int i = t; i < ecnt; i += 256) {
    int b = bidbuf[i];
    int pos = gbase[b] + (i - lstart[b]);
    if (pos < BCAP) gPairs[b * BCAP + pos] = pairbuf[i];
  }
}

__global__ __launch_bounds__(1024) void bscan_kernel(const int* __restrict__ gCursor,
                                                     int* __restrict__ bucketBase) {
  __shared__ int sm[1024];
  int t = threadIdx.x;
  int v = (t < NBUCKETS) ? min(gCursor[t], BCAP) : 0;
  sm[t] = v;
  __syncthreads();
  for (int off = 1; off < 1024; off <<= 1) {
    int x = (t >= off) ? sm[t - off] : 0;
    __syncthreads();
    sm[t] += x;
    __syncthreads();
  }
  bucketBase[t] = sm[t] - v;
  if (t == NBUCKETS - 1) bucketBase[NBUCKETS] = sm[t];
}

// ---------------- stage 2: per-bucket sort by srcPart (13 bins) ----------------
// sEdges entry keeps the packed (dl<<17)|src word, part-major order.

__global__ __launch_bounds__(256) void psort_kernel(const int* __restrict__ gCursor,
                                                    const int* __restrict__ bucketBase,
                                                    const uint_t* __restrict__ gPairs,
                                                    uint_t* __restrict__ sEdges) {
  __shared__ uint_t vals[BCAP];
  __shared__ int hist[NPARTS];
  __shared__ int cur[NPARTS];

  const int b = blockIdx.x, t = threadIdx.x;
  const int cnt = min(gCursor[b], BCAP);
  const int base = bucketBase[b];

  if (t < NPARTS) hist[t] = 0;
  __syncthreads();
  for (int i = t; i < cnt; i += 256) {
    uint_t v = gPairs[b * BCAP + i];
    vals[i] = v;
    atomicAdd(&hist[(v & 0x1FFFFu) >> 13], 1);
  }
  __syncthreads();
  if (t == 0) {
    int ex = 0;
    #pragma unroll
    for (int p = 0; p < NPARTS; ++p) { cur[p] = ex; ex += hist[p]; }
  }
  __syncthreads();
  for (int i = t; i < cnt; i += 256) {
    uint_t v = vals[i];
    int p = atomicAdd(&cur[(v & 0x1FFFFu) >> 13], 1);
    sEdges[base + p] = v;
  }
}

// ---------------- fused layer: edge-parallel agg (LDS f32 atomics) + MLP ----------------
// block = 128-node bucket. Phase A: 32 edge-slots x 8 dim-lanes sweep the part-ordered
// edge list; each edge gathers a 128B row and ds_add_f32's into zs. Phase B: 2x matmul.

__global__ __launch_bounds__(256) void layer_kernel(const ushort_t* __restrict__ h,
                                                    ushort_t* __restrict__ hout,
                                                    const int* __restrict__ bucketBase,
                                                    const uint_t* __restrict__ sEdges,
                                                    const float* __restrict__ W1,
                                                    const float* __restrict__ b1,
                                                    const float* __restrict__ gam,
                                                    const float* __restrict__ bet,
                                                    const float* __restrict__ W2,
                                                    const float* __restrict__ b2) {
  __shared__ float zs[128 * ZSTRIDE];
  __shared__ float wls[4096];

  const int t = threadIdx.x;
  const int b = blockIdx.x;
  const int base = b * 128;

  // ---- init zs = h rows (fp32), zero for OOB nodes ----
  #pragma unroll
  for (int i = 0; i < 4; ++i) {
    int f = i * 256 + t;                 // 0..1023 uint4 slots
    int nl = f >> 3;
    int seg = (f & 7) << 3;              // dim base 0,8,..,56
    int node = base + nl;
    float4 z0, z1;
    if (node < N_NODES) {
      uint4 r = *(const uint4*)(h + (size_t)node * DIM + seg);
      z0 = make_float4(bf2f(r.x & 0xffffu), bf2f(r.x >> 16),
                       bf2f(r.y & 0xffffu), bf2f(r.y >> 16));
      z1 = make_float4(bf2f(r.z & 0xffffu), bf2f(r.z >> 16),
                       bf2f(r.w & 0xffffu), bf2f(r.w >> 16));
    } else {
      z0 = make_float4(0.f, 0.f, 0.f, 0.f);
      z1 = z0;
    }
    *(float4*)(zs + nl * ZSTRIDE + seg) = z0;
    *(float4*)(zs + nl * ZSTRIDE + seg + 4) = z1;
  }
  __syncthreads();

  // ---- phase A: edge-parallel gather + LDS atomic accumulate ----
  {
    const int ebase = bucketBase[b];
    const int ecnt = bucketBase[b + 1] - ebase;
    const int slot = t >> 3;             // 0..31
    const int dp = (t & 7) << 3;         // dim base

    for (int e0 = 0; e0 < ecnt; e0 += 32) {
      int e = e0 + slot;
      if (e < ecnt) {
        uint_t v = sEdges[ebase + e];
        int u = (int)(v & 0x1FFFFu);
        int dl = (int)((v >> 17) & 127u);
        uint4 r = *(const uint4*)(h + (size_t)u * DIM + dp);
        float* zp = zs + dl * ZSTRIDE + dp;
        atomicAdd(zp + 0, bf2f(r.x & 0xffffu));
        atomicAdd(zp + 1, bf2f(r.x >> 16));
        atomicAdd(zp + 2, bf2f(r.y & 0xffffu));
        atomicAdd(zp + 3, bf2f(r.y >> 16));
        atomicAdd(zp + 4, bf2f(r.z & 0xffffu));
        atomicAdd(zp + 5, bf2f(r.z >> 16));
        atomicAdd(zp + 6, bf2f(r.w & 0xffffu));
        atomicAdd(zp + 7, bf2f(r.w >> 16));
      }
    }
  }
  __syncthreads();

  // ---- phase B: MLP, thread -> 4 nodes x 8 dims ----
  #pragma unroll
  for (int i = 0; i < 4; ++i) {
    int f = (i * 256 + t) * 4;
    *(float4*)(wls + f) = *(const float4*)(W1 + f);
  }
  __syncthreads();

  const int m = t & 7;
  const int gq = t >> 3;               // 0..31
  const int c0 = m * 8;

  float acc[4][8];
  #pragma unroll
  for (int j = 0; j < 4; ++j)
    #pragma unroll
    for (int i = 0; i < 8; ++i) acc[j][i] = 0.f;

  #pragma unroll 2
  for (int k0 = 0; k0 < 64; k0 += 4) {
    float zv[4][4];
    #pragma unroll
    for (int j = 0; j < 4; ++j)
      *(float4*)zv[j] = *(const float4*)(zs + (gq + 32 * j) * ZSTRIDE + k0);
    #pragma unroll
    for (int kk = 0; kk < 4; ++kk) {
      float wa[8];
      *(float4*)&wa[0] = *(const float4*)(wls + (k0 + kk) * 64 + c0);
      *(float4*)&wa[4] = *(const float4*)(wls + (k0 + kk) * 64 + c0 + 4);
      #pragma unroll
      for (int j = 0; j < 4; ++j) {
        float zz = zv[j][kk];
        #pragma unroll
        for (int i = 0; i < 8; ++i) acc[j][i] = fmaf(zz, wa[i], acc[j][i]);
      }
    }
  }

  const float BNR = 0.99999500003749971893f;   // 1/sqrt(1+1e-5)
  float s_[8], o_[8];
  #pragma unroll
  for (int i = 0; i < 8; ++i) {
    float sc = gam[c0 + i] * BNR;
    s_[i] = sc;
    o_[i] = fmaf(b1[c0 + i], sc, bet[c0 + i]);
  }
  #pragma unroll
  for (int j = 0; j < 4; ++j)
    #pragma unroll
    for (int i = 0; i < 8; ++i) {
      float v = fmaf(acc[j][i], s_[i], o_[i]);
      acc[j][i] = v > 0.f ? v : 0.f;
    }

  __syncthreads();   // matmul1 zs reads done

  #pragma unroll
  for (int j = 0; j < 4; ++j) {
    int n = gq + 32 * j;
    *(float4*)(zs + n * ZSTRIDE + c0)     = make_float4(acc[j][0], acc[j][1], acc[j][2], acc[j][3]);
    *(float4*)(zs + n * ZSTRIDE + c0 + 4) = make_float4(acc[j][4], acc[j][5], acc[j][6], acc[j][7]);
  }
  #pragma unroll
  for (int i = 0; i < 4; ++i) {
    int f = (i * 256 + t) * 4;
    *(float4*)(wls + f) = *(const float4*)(W2 + f);
  }
  __syncthreads();

  float acc2[4][8];
  #pragma unroll
  for (int j = 0; j < 4; ++j)
    #pragma unroll
    for (int i = 0; i < 8; ++i) acc2[j][i] = 0.f;

  #pragma unroll 2
  for (int k0 = 0; k0 < 64; k0 += 4) {
    float zv[4][4];
    #pragma unroll
    for (int j = 0; j < 4; ++j)
      *(float4*)zv[j] = *(const float4*)(zs + (gq + 32 * j) * ZSTRIDE + k0);
    #pragma unroll
    for (int kk = 0; kk < 4; ++kk) {
      float wa[8];
      *(float4*)&wa[0] = *(const float4*)(wls + (k0 + kk) * 64 + c0);
      *(float4*)&wa[4] = *(const float4*)(wls + (k0 + kk) * 64 + c0 + 4);
      #pragma unroll
      for (int j = 0; j < 4; ++j) {
        float zz = zv[j][kk];
        #pragma unroll
        for (int i = 0; i < 8; ++i) acc2[j][i] = fmaf(zz, wa[i], acc2[j][i]);
      }
    }
  }

  float bb[8];
  #pragma unroll
  for (int i = 0; i < 8; ++i) bb[i] = b2[c0 + i];
  #pragma unroll
  for (int j = 0; j < 4; ++j) {
    int gn = base + gq + 32 * j;
    if (gn < N_NODES) {
      uint4 o;
      float v0 = fmaxf(acc2[j][0] + bb[0], 0.f);
      float v1 = fmaxf(acc2[j][1] + bb[1], 0.f);
      float v2 = fmaxf(acc2[j][2] + bb[2], 0.f);
      float v3 = fmaxf(acc2[j][3] + bb[3], 0.f);
      float v4 = fmaxf(acc2[j][4] + bb[4], 0.f);
      float v5 = fmaxf(acc2[j][5] + bb[5], 0.f);
      float v6 = fmaxf(acc2[j][6] + bb[6], 0.f);
      float v7 = fmaxf(acc2[j][7] + bb[7], 0.f);
      o.x = pack2(v0, v1);
      o.y = pack2(v2, v3);
      o.z = pack2(v4, v5);
      o.w = pack2(v6, v7);
      *(uint4*)(hout + (size_t)gn * DIM + c0) = o;
    }
  }
}

// ---------------- pool: partial sums (batch sorted) + tiny head ----------------

__global__ __launch_bounds__(256) void pool_partial_kernel(const ushort_t* __restrict__ h,
                                                           const int* __restrict__ batch,
                                                           float* __restrict__ pooled) {
  int r0 = blockIdx.x * POOL_CH;
  int rend = min(r0 + POOL_CH, N_NODES);
  int w = threadIdx.x >> 6, d = threadIdx.x & 63;
  float acc = 0.f;
  int curg = -1;
  for (int i = r0 + w; i < rend; i += 4) {
    int g = batch[i];
    if (g != curg) {
      if (curg >= 0) atomicAdd(&pooled[curg * DIM + d], acc);
      acc = 0.f;
      curg = g;
    }
    acc += bf2f((uint_t)h[i * DIM + d]);
  }
  if (curg >= 0) atomicAdd(&pooled[curg * DIM + d], acc);
}

__global__ __launch_bounds__(256) void head_kernel(const float* __restrict__ pooled,
                                                   const float* __restrict__ lw,
                                                   const float* __restrict__ lb,
                                                   float* __restrict__ out) {
  int idx = blockIdx.x * 256 + threadIdx.x;
  if (idx >= N_GRAPHS * DIM) return;
  int g = idx >> 6, d = idx & 63;
  float o = lb[d];
  #pragma unroll 8
  for (int k = 0; k < 64; ++k) o = fmaf(pooled[g * 64 + k], lw[k * 64 + d], o);
  out[idx] = fmaxf(o, 0.f);
}

// ---------------- host ----------------

extern "C" void kernel_launch(void* const* d_in, const int* in_sizes, int n_in,
                              void* d_out, int out_size, void* d_ws, size_t ws_size,
                              hipStream_t stream) {
  const float* x      = (const float*)d_in[0];
  const int*   ei     = (const int*)d_in[1];
  const int*   srcp   = ei;
  const int*   dstp   = ei + N_EDGES;
  const int*   batch  = (const int*)d_in[2];
  const float* W1s    = (const float*)d_in[3];
  const float* b1s    = (const float*)d_in[4];
  const float* gammas = (const float*)d_in[5];
  const float* betas  = (const float*)d_in[6];
  const float* W2s    = (const float*)d_in[7];
  const float* b2s    = (const float*)d_in[8];
  const float* lin1_w = (const float*)d_in[9];
  const float* lin1_b = (const float*)d_in[10];

  char* p = (char*)d_ws;
  ushort_t* xb     = (ushort_t*)p; p += (size_t)N_NODES * DIM * 2;      // 12.8 MB
  ushort_t* h1     = (ushort_t*)p; p += (size_t)N_NODES * DIM * 2;      // 12.8 MB
  uint_t*   gPairs = (uint_t*)p;   p += (size_t)NBUCKETS * BCAP * 4;    // 6.4 MB
  uint_t*   sEdges = (uint_t*)p;   p += (size_t)N_EDGES * 4;            // 4.8 MB
  int*      gCursor    = (int*)p;  p += 4096;
  int*      bucketBase = (int*)p;  p += 4096;
  float*    pooled     = (float*)p;

  hipMemsetAsync(gCursor, 0, 1024 * sizeof(int), stream);
  hipMemsetAsync(pooled, 0, N_GRAPHS * DIM * sizeof(float), stream);
  conv_kernel<<<(N_NODES * DIM / 8 + 255) / 256, 256, 0, stream>>>(x, xb);

  const int BIN_BLOCKS = (N_EDGES + CHUNK - 1) / CHUNK;   // 147
  bin_kernel<<<BIN_BLOCKS, 256, 0, stream>>>(srcp, dstp, gCursor, gPairs);
  bscan_kernel<<<1, 1024, 0, stream>>>(gCursor, bucketBase);
  psort_kernel<<<NBUCKETS, 256, 0, stream>>>(gCursor, bucketBase, gPairs, sEdges);

  const ushort_t* hin = xb;
  for (int l = 0; l < N_LAYERS; ++l) {
    ushort_t* hout = (l & 1) ? xb : h1;
    layer_kernel<<<NBUCKETS, 256, 0, stream>>>(hin, hout, bucketBase, sEdges,
        W1s + (size_t)l * DIM * DIM, b1s + (size_t)l * DIM,
        gammas + (size_t)l * DIM, betas + (size_t)l * DIM,
        W2s + (size_t)l * DIM * DIM, b2s + (size_t)l * DIM);
    hin = hout;
  }

  pool_partial_kernel<<<POOL_BLOCKS, 256, 0, stream>>>(h1, batch, pooled);
  head_kernel<<<(N_GRAPHS * DIM + 255) / 256, 256, 0, stream>>>(pooled, lin1_w, lin1_b, (float*)d_out);
}

// Round 7
// 343.878 us; speedup vs baseline: 7.7826x; 7.7826x over previous
//
#include <hip/hip_runtime.h>

#define N_NODES 100000
#define N_EDGES 1200000
#define DIM 64
#define N_GRAPHS 128
#define N_LAYERS 5

#define NBUCKETS 782          // ceil(100000/128)
#define BCAP 2048             // per-bucket capacity (mean 1534, +13 sigma)
#define CHUNK 8192            // edges per bin block

#define POOL_CH 196
#define POOL_BLOCKS ((N_NODES + POOL_CH - 1) / POOL_CH)

#define WSTR 72               // bf16 LDS row stride (144B): 2-way bank aliasing only

typedef unsigned short ushort_t;
typedef unsigned int uint_t;
typedef __attribute__((ext_vector_type(8))) short short8v;   // 8 bf16 = 4 VGPR
typedef __attribute__((ext_vector_type(4))) float float4v;

__device__ __forceinline__ float bf2f(uint_t s) {
  return __uint_as_float(s << 16);
}
__device__ __forceinline__ ushort_t f2bf(float f) {
  uint_t u = __float_as_uint(f);
  uint_t r = u + 0x7fffu + ((u >> 16) & 1u);   // RNE
  return (ushort_t)(r >> 16);
}
__device__ __forceinline__ uint_t pack2(float a, float b) {
  return (uint_t)f2bf(a) | ((uint_t)f2bf(b) << 16);
}

// ---------------- fp32 -> bf16 convert (x only, once) ----------------

__global__ __launch_bounds__(256) void conv_kernel(const float* __restrict__ x,
                                                   ushort_t* __restrict__ xb) {
  int i = blockIdx.x * 256 + threadIdx.x;
  int base = i * 8;
  if (base >= N_NODES * DIM) return;
  float4 a = *(const float4*)(x + base);
  float4 b = *(const float4*)(x + base + 4);
  uint4 o;
  o.x = pack2(a.x, a.y);
  o.y = pack2(a.z, a.w);
  o.z = pack2(b.x, b.y);
  o.w = pack2(b.z, b.w);
  *(uint4*)(xb + base) = o;
}

// ---------------- CSR build stage 1: LDS multisplit into 782 buckets ----------------

__global__ __launch_bounds__(256) void bin_kernel(const int* __restrict__ src,
                                                  const int* __restrict__ dst,
                                                  int* __restrict__ gCursor,
                                                  uint_t* __restrict__ gPairs) {
  __shared__ int hist[NBUCKETS];
  __shared__ int lstart[NBUCKETS];
  __shared__ int lcur[NBUCKETS];
  __shared__ int gbase[NBUCKETS];
  __shared__ uint_t pairbuf[CHUNK];
  __shared__ ushort_t bidbuf[CHUNK];
  __shared__ int wsum[4];

  const int t = threadIdx.x;
  const int e0 = blockIdx.x * CHUNK;
  const int ecnt = min(CHUNK, N_EDGES - e0);

  for (int i = t; i < NBUCKETS; i += 256) hist[i] = 0;
  __syncthreads();

  for (int i = t; i < ecnt; i += 256) {
    int d = dst[e0 + i];
    atomicAdd(&hist[d >> 7], 1);
  }
  __syncthreads();

  const int base4 = t * 4;
  int h0 = 0, h1 = 0, h2 = 0, h3 = 0;
  if (base4 + 0 < NBUCKETS) h0 = hist[base4 + 0];
  if (base4 + 1 < NBUCKETS) h1 = hist[base4 + 1];
  if (base4 + 2 < NBUCKETS) h2 = hist[base4 + 2];
  if (base4 + 3 < NBUCKETS) h3 = hist[base4 + 3];
  int tsum = h0 + h1 + h2 + h3;
  int lane = t & 63, wid = t >> 6;
  int inc = tsum;
  #pragma unroll
  for (int off = 1; off < 64; off <<= 1) {
    int v = __shfl_up(inc, off);
    if (lane >= off) inc += v;
  }
  if (lane == 63) wsum[wid] = inc;
  __syncthreads();
  int wadd = 0;
  for (int w = 0; w < wid; ++w) wadd += wsum[w];
  int ex = wadd + inc - tsum;
  if (base4 + 0 < NBUCKETS) { lstart[base4 + 0] = ex; lcur[base4 + 0] = ex; } ex += h0;
  if (base4 + 1 < NBUCKETS) { lstart[base4 + 1] = ex; lcur[base4 + 1] = ex; } ex += h1;
  if (base4 + 2 < NBUCKETS) { lstart[base4 + 2] = ex; lcur[base4 + 2] = ex; } ex += h2;
  if (base4 + 3 < NBUCKETS) { lstart[base4 + 3] = ex; lcur[base4 + 3] = ex; }
  __syncthreads();

  for (int i = t; i < ecnt; i += 256) {
    int s = src[e0 + i];
    int d = dst[e0 + i];
    int b = d >> 7;
    int p = atomicAdd(&lcur[b], 1);
    pairbuf[p] = (uint_t)s | ((uint_t)(d & 127) << 17);
    bidbuf[p] = (ushort_t)b;
  }
  __syncthreads();

  for (int b = t; b < NBUCKETS; b += 256) {
    int cnt = lcur[b] - lstart[b];
    gbase[b] = cnt ? atomicAdd(&gCursor[b], cnt) : 0;
  }
  __syncthreads();

  for (int i = t; i < ecnt; i += 256) {
    int b = bidbuf[i];
    int pos = gbase[b] + (i - lstart[b]);
    if (pos < BCAP) gPairs[b * BCAP + pos] = pairbuf[i];
  }
}

__global__ __launch_bounds__(1024) void bscan_kernel(const int* __restrict__ gCursor,
                                                     int* __restrict__ bucketBase) {
  __shared__ int sm[1024];
  int t = threadIdx.x;
  int v = (t < NBUCKETS) ? min(gCursor[t], BCAP) : 0;
  sm[t] = v;
  __syncthreads();
  for (int off = 1; off < 1024; off <<= 1) {
    int x = (t >= off) ? sm[t - off] : 0;
    __syncthreads();
    sm[t] += x;
    __syncthreads();
  }
  bucketBase[t] = sm[t] - v;
  if (t == NBUCKETS - 1) bucketBase[NBUCKETS] = sm[t];
}

// per-bucket counting sort -> rowptr + ssrc
__global__ __launch_bounds__(256) void csort_kernel(const int* __restrict__ gCursor,
                                                    const int* __restrict__ bucketBase,
                                                    const uint_t* __restrict__ gPairs,
                                                    int* __restrict__ rowptr,
                                                    int* __restrict__ ssrc) {
  __shared__ uint_t vals[BCAP];
  __shared__ int ssl[BCAP];
  __shared__ int nh[128];
  __shared__ int ncur[128];
  __shared__ int w0sum;

  const int b = blockIdx.x, t = threadIdx.x;
  const int cnt = min(gCursor[b], BCAP);
  const int base = bucketBase[b];
  const int n0 = b << 7;
  const int nn = min(128, N_NODES - n0);

  if (t < 128) nh[t] = 0;
  __syncthreads();
  for (int i = t; i < cnt; i += 256) {
    uint_t v = gPairs[b * BCAP + i];
    vals[i] = v;
    atomicAdd(&nh[(v >> 17) & 127], 1);
  }
  __syncthreads();

  int inc = 0, v = 0;
  if (t < 128) {
    v = nh[t];
    inc = v;
    int lane = t & 63;
    #pragma unroll
    for (int off = 1; off < 64; off <<= 1) {
      int x = __shfl_up(inc, off);
      if (lane >= off) inc += x;
    }
    if (t == 63) w0sum = inc;
  }
  __syncthreads();
  if (t < 128) {
    int e = inc - v + ((t >= 64) ? w0sum : 0);
    ncur[t] = e;
    if (t < nn) rowptr[n0 + t] = base + e;
  }
  if (b == NBUCKETS - 1 && t == 0) rowptr[N_NODES] = base + cnt;
  __syncthreads();

  for (int i = t; i < cnt; i += 256) {
    uint_t vv = vals[i];
    int j = (vv >> 17) & 127;
    int p = atomicAdd(&ncur[j], 1);
    ssl[p] = (int)(vv & 0x1FFFF);
  }
  __syncthreads();
  for (int i = t; i < cnt; i += 256) ssrc[base + i] = ssl[i];
}

// ---------------- aggregation: z = h + sum_{j in N(i)} h_j  (z out = bf16) ----------------
// 8 edges per wave-load: lane l -> edge slot l>>3, dims ((l&7)*8) as uint4 (16B).

__global__ __launch_bounds__(256) void agg_kernel(const ushort_t* __restrict__ h,
                                                  const int* __restrict__ rowptr,
                                                  const int* __restrict__ ssrc,
                                                  ushort_t* __restrict__ zb) {
  int node = blockIdx.x * 4 + (threadIdx.x >> 6);
  int l = threadIdx.x & 63;
  if (node >= N_NODES) return;
  int sub = l >> 3;           // 0..7 (edge slot within group)
  int dp = (l & 7) << 3;      // dim base: 0,8,..,56
  float a[8];
  #pragma unroll
  for (int i = 0; i < 8; ++i) a[i] = 0.f;
  if (sub == 0) {
    uint4 r = *(const uint4*)(h + (size_t)node * DIM + dp);
    a[0] = bf2f(r.x & 0xffffu); a[1] = bf2f(r.x >> 16);
    a[2] = bf2f(r.y & 0xffffu); a[3] = bf2f(r.y >> 16);
    a[4] = bf2f(r.z & 0xffffu); a[5] = bf2f(r.z >> 16);
    a[6] = bf2f(r.w & 0xffffu); a[7] = bf2f(r.w >> 16);
  }
  int s = rowptr[node], e = rowptr[node + 1];
  for (int j = s; j < e; j += 8) {
    int idx = j + sub;
    if (idx < e) {
      int u = ssrc[idx];
      uint4 r = *(const uint4*)(h + (size_t)u * DIM + dp);
      a[0] += bf2f(r.x & 0xffffu); a[1] += bf2f(r.x >> 16);
      a[2] += bf2f(r.y & 0xffffu); a[3] += bf2f(r.y >> 16);
      a[4] += bf2f(r.z & 0xffffu); a[5] += bf2f(r.z >> 16);
      a[6] += bf2f(r.w & 0xffffu); a[7] += bf2f(r.w >> 16);
    }
  }
  #pragma unroll
  for (int i = 0; i < 8; ++i) {
    a[i] += __shfl_xor(a[i], 8);
    a[i] += __shfl_xor(a[i], 16);
    a[i] += __shfl_xor(a[i], 32);
  }
  if (sub == 0) {
    uint4 o;
    o.x = pack2(a[0], a[1]);
    o.y = pack2(a[2], a[3]);
    o.z = pack2(a[4], a[5]);
    o.w = pack2(a[6], a[7]);
    *(uint4*)(zb + (size_t)node * DIM + dp) = o;
  }
}

// ---------------- MFMA MLP: hout = relu((relu(bn(z@W1+b1)))@W2+b2) ----------------
// 128-node tile, 256 threads (4 waves). Wave w owns rows 32w..32w+31 end-to-end.
// A-frag: row = lane&15, k = (lane>>4)*8 + j.  B-frag: col = lane&15, same k.
// C/D: col = lane&15, row = (lane>>4)*4 + reg  [HW-verified mapping].

__global__ __launch_bounds__(256) void mlp_kernel(const ushort_t* __restrict__ zb,
                                                  ushort_t* __restrict__ hout,
                                                  const float* __restrict__ W1,
                                                  const float* __restrict__ b1,
                                                  const float* __restrict__ gam,
                                                  const float* __restrict__ bet,
                                                  const float* __restrict__ W2,
                                                  const float* __restrict__ b2) {
  __shared__ ushort_t zs[128 * WSTR];    // 18432 B
  __shared__ ushort_t wt1[64 * WSTR];    // 9216 B, W1^T bf16
  __shared__ ushort_t wt2[64 * WSTR];    // 9216 B, W2^T bf16

  const int t = threadIdx.x;
  const int base = blockIdx.x * 128;

  // stage z tile (bf16, coalesced 16B loads)
  #pragma unroll
  for (int i = 0; i < 4; ++i) {
    int f = i * 256 + t;
    int row = f >> 3, seg = (f & 7) << 3;
    int gn = base + row;
    if (gn >= N_NODES) gn = N_NODES - 1;     // clamp; garbage rows never stored
    *(uint4*)(zs + row * WSTR + seg) = *(const uint4*)(zb + (size_t)gn * DIM + seg);
  }
  // stage W1^T / W2^T as bf16
  for (int idx = t; idx < 4096; idx += 256) {
    int k = idx >> 6, n = idx & 63;
    wt1[n * WSTR + k] = f2bf(W1[idx]);
    wt2[n * WSTR + k] = f2bf(W2[idx]);
  }
  __syncthreads();

  const int lane = t & 63;
  const int w = t >> 6;
  const int lr = lane & 15;        // A row / B col / D col
  const int kc = lane >> 4;        // k-chunk 0..3 (D row group)

  const float BNR = 0.99999500003749971893f;   // 1/sqrt(1+1e-5)
  float s_[4], o_[4], bb_[4];
  #pragma unroll
  for (int nt = 0; nt < 4; ++nt) {
    int od = nt * 16 + lr;
    float sc = gam[od] * BNR;
    s_[nt] = sc;
    o_[nt] = fmaf(b1[od], sc, bet[od]);
    bb_[nt] = b2[od];
  }

  float4v acc[2][4];
  #pragma unroll
  for (int mt = 0; mt < 2; ++mt)
    #pragma unroll
    for (int nt = 0; nt < 4; ++nt)
      acc[mt][nt] = (float4v){0.f, 0.f, 0.f, 0.f};

  // ---- matmul1: z @ W1 ----
  #pragma unroll
  for (int k0 = 0; k0 < 2; ++k0) {
    short8v bfr[4];
    #pragma unroll
    for (int nt = 0; nt < 4; ++nt)
      bfr[nt] = *(short8v*)(wt1 + (nt * 16 + lr) * WSTR + k0 * 32 + kc * 8);
    #pragma unroll
    for (int mt = 0; mt < 2; ++mt) {
      short8v afr = *(short8v*)(zs + ((w * 2 + mt) * 16 + lr) * WSTR + k0 * 32 + kc * 8);
      #pragma unroll
      for (int nt = 0; nt < 4; ++nt)
        acc[mt][nt] = __builtin_amdgcn_mfma_f32_16x16x32_bf16(afr, bfr[nt], acc[mt][nt], 0, 0, 0);
    }
  }

  // ---- BN fold + relu, write z1 (bf16) back over own zs rows ----
  #pragma unroll
  for (int mt = 0; mt < 2; ++mt)
    #pragma unroll
    for (int nt = 0; nt < 4; ++nt)
      #pragma unroll
      for (int r = 0; r < 4; ++r) {
        float v = fmaf(acc[mt][nt][r], s_[nt], o_[nt]);
        v = v > 0.f ? v : 0.f;
        int node = (w * 2 + mt) * 16 + kc * 4 + r;   // own rows only
        zs[node * WSTR + nt * 16 + lr] = f2bf(v);
      }

  #pragma unroll
  for (int mt = 0; mt < 2; ++mt)
    #pragma unroll
    for (int nt = 0; nt < 4; ++nt)
      acc[mt][nt] = (float4v){0.f, 0.f, 0.f, 0.f};

  // ---- matmul2: z1 @ W2 (reads own zs rows, written by this wave) ----
  #pragma unroll
  for (int k0 = 0; k0 < 2; ++k0) {
    short8v bfr[4];
    #pragma unroll
    for (int nt = 0; nt < 4; ++nt)
      bfr[nt] = *(short8v*)(wt2 + (nt * 16 + lr) * WSTR + k0 * 32 + kc * 8);
    #pragma unroll
    for (int mt = 0; mt < 2; ++mt) {
      short8v afr = *(short8v*)(zs + ((w * 2 + mt) * 16 + lr) * WSTR + k0 * 32 + kc * 8);
      #pragma unroll
      for (int nt = 0; nt < 4; ++nt)
        acc[mt][nt] = __builtin_amdgcn_mfma_f32_16x16x32_bf16(afr, bfr[nt], acc[mt][nt], 0, 0, 0);
    }
  }

  // ---- bias + relu, write bf16 result to own zs rows ----
  #pragma unroll
  for (int mt = 0; mt < 2; ++mt)
    #pragma unroll
    for (int nt = 0; nt < 4; ++nt)
      #pragma unroll
      for (int r = 0; r < 4; ++r) {
        float v = acc[mt][nt][r] + bb_[nt];
        v = v > 0.f ? v : 0.f;
        int node = (w * 2 + mt) * 16 + kc * 4 + r;
        zs[node * WSTR + nt * 16 + lr] = f2bf(v);
      }
  __syncthreads();

  // ---- coalesced copy-out ----
  #pragma unroll
  for (int i = 0; i < 4; ++i) {
    int f = i * 256 + t;
    int row = f >> 3, seg = (f & 7) << 3;
    int gn = base + row;
    if (gn < N_NODES)
      *(uint4*)(hout + (size_t)gn * DIM + seg) = *(const uint4*)(zs + row * WSTR + seg);
  }
}

// ---------------- pool: partial sums (batch sorted) + tiny head ----------------

__global__ __launch_bounds__(256) void pool_partial_kernel(const ushort_t* __restrict__ h,
                                                           const int* __restrict__ batch,
                                                           float* __restrict__ pooled) {
  int r0 = blockIdx.x * POOL_CH;
  int rend = min(r0 + POOL_CH, N_NODES);
  int w = threadIdx.x >> 6, d = threadIdx.x & 63;
  float acc = 0.f;
  int curg = -1;
  for (int i = r0 + w; i < rend; i += 4) {
    int g = batch[i];
    if (g != curg) {
      if (curg >= 0) atomicAdd(&pooled[curg * DIM + d], acc);
      acc = 0.f;
      curg = g;
    }
    acc += bf2f((uint_t)h[i * DIM + d]);
  }
  if (curg >= 0) atomicAdd(&pooled[curg * DIM + d], acc);
}

__global__ __launch_bounds__(256) void head_kernel(const float* __restrict__ pooled,
                                                   const float* __restrict__ lw,
                                                   const float* __restrict__ lb,
                                                   float* __restrict__ out) {
  int idx = blockIdx.x * 256 + threadIdx.x;
  if (idx >= N_GRAPHS * DIM) return;
  int g = idx >> 6, d = idx & 63;
  float o = lb[d];
  #pragma unroll 8
  for (int k = 0; k < 64; ++k) o = fmaf(pooled[g * 64 + k], lw[k * 64 + d], o);
  out[idx] = fmaxf(o, 0.f);
}

// ---------------- host ----------------

extern "C" void kernel_launch(void* const* d_in, const int* in_sizes, int n_in,
                              void* d_out, int out_size, void* d_ws, size_t ws_size,
                              hipStream_t stream) {
  const float* x      = (const float*)d_in[0];
  const int*   ei     = (const int*)d_in[1];
  const int*   srcp   = ei;
  const int*   dstp   = ei + N_EDGES;
  const int*   batch  = (const int*)d_in[2];
  const float* W1s    = (const float*)d_in[3];
  const float* b1s    = (const float*)d_in[4];
  const float* gammas = (const float*)d_in[5];
  const float* betas  = (const float*)d_in[6];
  const float* W2s    = (const float*)d_in[7];
  const float* b2s    = (const float*)d_in[8];
  const float* lin1_w = (const float*)d_in[9];
  const float* lin1_b = (const float*)d_in[10];

  char* p = (char*)d_ws;
  ushort_t* xb     = (ushort_t*)p; p += (size_t)N_NODES * DIM * 2;      // 12.8 MB
  ushort_t* h1     = (ushort_t*)p; p += (size_t)N_NODES * DIM * 2;      // 12.8 MB
  ushort_t* zbuf   = (ushort_t*)p; p += (size_t)N_NODES * DIM * 2;      // 12.8 MB
  uint_t*   gPairs = (uint_t*)p;   p += (size_t)NBUCKETS * BCAP * 4;    // 6.4 MB
  int*      ssrc   = (int*)p;      p += (size_t)N_EDGES * 4;            // 4.8 MB
  int*      rowptr = (int*)p;      p += 100352 * sizeof(int);
  int*      gCursor    = (int*)p;  p += 4096;
  int*      bucketBase = (int*)p;  p += 4096;
  float*    pooled     = (float*)p;

  hipMemsetAsync(gCursor, 0, 1024 * sizeof(int), stream);
  hipMemsetAsync(pooled, 0, N_GRAPHS * DIM * sizeof(float), stream);
  conv_kernel<<<(N_NODES * DIM / 8 + 255) / 256, 256, 0, stream>>>(x, xb);

  const int BIN_BLOCKS = (N_EDGES + CHUNK - 1) / CHUNK;   // 147
  bin_kernel<<<BIN_BLOCKS, 256, 0, stream>>>(srcp, dstp, gCursor, gPairs);
  bscan_kernel<<<1, 1024, 0, stream>>>(gCursor, bucketBase);
  csort_kernel<<<NBUCKETS, 256, 0, stream>>>(gCursor, bucketBase, gPairs, rowptr, ssrc);

  const int AGG_BLOCKS = (N_NODES + 3) / 4;          // 25000
  const int MLP_BLOCKS = NBUCKETS;                   // 782

  const ushort_t* hin = xb;
  for (int l = 0; l < N_LAYERS; ++l) {
    ushort_t* hout = (l & 1) ? xb : h1;
    agg_kernel<<<AGG_BLOCKS, 256, 0, stream>>>(hin, rowptr, ssrc, zbuf);
    mlp_kernel<<<MLP_BLOCKS, 256, 0, stream>>>(zbuf, hout,
        W1s + (size_t)l * DIM * DIM, b1s + (size_t)l * DIM,
        gammas + (size_t)l * DIM, betas + (size_t)l * DIM,
        W2s + (size_t)l * DIM * DIM, b2s + (size_t)l * DIM);
    hin = hout;
  }

  pool_partial_kernel<<<POOL_BLOCKS, 256, 0, stream>>>(h1, batch, pooled);
  head_kernel<<<(N_GRAPHS * DIM + 255) / 256, 256, 0, stream>>>(pooled, lin1_w, lin1_b, (float*)d_out);
}